// Round 1
// 1168.933 us; speedup vs baseline: 1.9944x; 1.9944x over previous
//
#include <hip/hip_runtime.h>
#include <math.h>

#define HH 16
#define DD 64
#define TS 2048
#define EE 1024
#define BB 4
#define MS 12.0f

typedef __attribute__((ext_vector_type(8))) __bf16 bf16x8;
typedef __attribute__((ext_vector_type(8))) _Float16 f16x8;
typedef __attribute__((ext_vector_type(4))) float f32x4;

__device__ __forceinline__ f32x4 mm3(bf16x8 ah, bf16x8 al, bf16x8 bh, bf16x8 bl, f32x4 c) {
    c = __builtin_amdgcn_mfma_f32_16x16x32_bf16(ah, bh, c, 0, 0, 0);
    c = __builtin_amdgcn_mfma_f32_16x16x32_bf16(ah, bl, c, 0, 0, 0);
    c = __builtin_amdgcn_mfma_f32_16x16x32_bf16(al, bh, c, 0, 0, 0);
    return c;
}

__device__ __forceinline__ void gll16(const void* g, void* l) {
    __builtin_amdgcn_global_load_lds(
        (const __attribute__((address_space(1))) unsigned int*)g,
        (__attribute__((address_space(3))) unsigned int*)l, 16, 0, 0);
}

__device__ __forceinline__ unsigned pk2(float p) {
    __bf16 h = (__bf16)p;
    __bf16 l = (__bf16)(p - (float)h);
    return ((unsigned)__builtin_bit_cast(unsigned short, h) << 16) |
            (unsigned)__builtin_bit_cast(unsigned short, l);
}
__device__ __forceinline__ float upk_hi(unsigned u) { return __builtin_bit_cast(float, u & 0xffff0000u); }
__device__ __forceinline__ float upk_lo(unsigned u) { return __builtin_bit_cast(float, u << 16); }

__device__ __forceinline__ bf16x8 sel_frag(uint4 a, uint4 b, unsigned s) {
    uint4 r;
    r.x = __builtin_amdgcn_perm(a.y, a.x, s);
    r.y = __builtin_amdgcn_perm(a.w, a.z, s);
    r.z = __builtin_amdgcn_perm(b.y, b.x, s);
    r.w = __builtin_amdgcn_perm(b.w, b.z, s);
    return __builtin_bit_cast(bf16x8, r);
}

// ---------------- fp32 -> bf16 hi/lo split (elementwise) ----------------
__global__ __launch_bounds__(256) void splitk(const float* __restrict__ src,
    __bf16* __restrict__ hi, __bf16* __restrict__ lo)
{
    size_t i = ((size_t)blockIdx.x * 256 + threadIdx.x) * 8;
    float4 a = *(const float4*)(src + i);
    float4 b = *(const float4*)(src + i + 4);
    float v[8] = {a.x, a.y, a.z, a.w, b.x, b.y, b.z, b.w};
    bf16x8 h, l;
    #pragma unroll
    for (int j = 0; j < 8; ++j) {
        __bf16 x = (__bf16)v[j];
        h[j] = x;
        l[j] = (__bf16)(v[j] - (float)x);
    }
    *(bf16x8*)(hi + i) = h;
    *(bf16x8*)(lo + i) = l;
}

// ---------------- 3-term split-bf16 MFMA GEMM: C[M,N] = A[M,K]*B[N,K]^T ----------------
// OMODE 0: f32 C[M,N];  1: hi/lo split to [B,H,T,D];  2: hi/lo split to [B,H,D,T]
template<int OMODE>
__global__ __launch_bounds__(256) void gemm3(
    const __bf16* __restrict__ Ah, const __bf16* __restrict__ Al,
    const __bf16* __restrict__ Bh, const __bf16* __restrict__ Bl,
    float* __restrict__ Cf, __bf16* __restrict__ Ch, __bf16* __restrict__ Cl,
    int M, int N, int K)
{
    __shared__ __bf16 sA[2][128 * 32];
    __shared__ __bf16 sB[2][128 * 32];
    const int tid = threadIdx.x, wave = tid >> 6, lane = tid & 63;
    const int quad = lane >> 4, l15 = lane & 15;
    const int m0 = blockIdx.y * 128, n0 = blockIdx.x * 128;
    const int wm = (wave >> 1) * 64, wn = (wave & 1) * 64;
    const int srow = lane >> 2, scol = (lane & 3) * 8;

    f32x4 acc[4][4];
    #pragma unroll
    for (int i = 0; i < 4; ++i)
        #pragma unroll
        for (int j = 0; j < 4; ++j)
            acc[i][j] = (f32x4){0.f, 0.f, 0.f, 0.f};

    for (int k0 = 0; k0 < K; k0 += 32) {
        __syncthreads();
        #pragma unroll
        for (int i = 0; i < 2; ++i) {
            int c = wave * 2 + i;
            size_t ga = (size_t)(m0 + c * 16 + srow) * K + k0 + scol;
            size_t gb = (size_t)(n0 + c * 16 + srow) * K + k0 + scol;
            gll16(Ah + ga, &sA[0][c * 512]);
            gll16(Al + ga, &sA[1][c * 512]);
            gll16(Bh + gb, &sB[0][c * 512]);
            gll16(Bl + gb, &sB[1][c * 512]);
        }
        __syncthreads();
        bf16x8 fAh[4], fAl[4], fBh[4], fBl[4];
        #pragma unroll
        for (int mb = 0; mb < 4; ++mb) {
            int r = (wm + mb * 16 + l15) * 32 + quad * 8;
            fAh[mb] = *(const bf16x8*)&sA[0][r];
            fAl[mb] = *(const bf16x8*)&sA[1][r];
        }
        #pragma unroll
        for (int nb = 0; nb < 4; ++nb) {
            int r = (wn + nb * 16 + l15) * 32 + quad * 8;
            fBh[nb] = *(const bf16x8*)&sB[0][r];
            fBl[nb] = *(const bf16x8*)&sB[1][r];
        }
        #pragma unroll
        for (int mb = 0; mb < 4; ++mb)
            #pragma unroll
            for (int nb = 0; nb < 4; ++nb)
                acc[mb][nb] = mm3(fAh[mb], fAl[mb], fBh[nb], fBl[nb], acc[mb][nb]);
    }

    #pragma unroll
    for (int mb = 0; mb < 4; ++mb)
        #pragma unroll
        for (int nb = 0; nb < 4; ++nb)
            #pragma unroll
            for (int r = 0; r < 4; ++r) {
                int m = m0 + wm + mb * 16 + quad * 4 + r;
                int n = n0 + wn + nb * 16 + l15;
                float v = acc[mb][nb][r];
                if (OMODE == 0) {
                    Cf[(size_t)m * N + n] = v;
                } else {
                    int b = m >> 11, t = m & (TS - 1);
                    int h = n >> 6,  d = n & (DD - 1);
                    __bf16 hi = (__bf16)v;
                    __bf16 lo = (__bf16)(v - (float)hi);
                    size_t off = (OMODE == 1)
                        ? ((((size_t)b * HH + h) * TS + t) * DD + d)
                        : ((((size_t)b * HH + h) * DD + d) * TS + t);
                    Ch[off] = hi;
                    Cl[off] = lo;
                }
            }
}

// ---------------- MFMA flash attention, wave=head, fixed-max softmax ----------------
// out1 partial sums: g==0 writes fp32 directly to out1 (scaled 1/16);
// g==1..3 write fp16 partials (scaled 1/16) to pp + (g-1)*B*T*S; no atomics.
__global__ __launch_bounds__(256) void attn3(
    const __bf16* __restrict__ Qh, const __bf16* __restrict__ Ql,
    const __bf16* __restrict__ Kh, const __bf16* __restrict__ Kl,
    const __bf16* __restrict__ VhT, const __bf16* __restrict__ VlT,
    __bf16* __restrict__ avh, __bf16* __restrict__ avl,
    float* __restrict__ out1, _Float16* __restrict__ pp)
{
    __shared__ unsigned Pt[4][32][68];   // packed (bf16 hi<<16 | lo), per-wave P tile
    const int tid = threadIdx.x, wave = tid >> 6, lane = tid & 63;
    const int quad = lane >> 4, l15 = lane & 15;
    // XCD-locality swizzle: each XCD works one (b,g) at a time (4 MB K/V set fits L2)
    const int linear = blockIdx.x + 64 * blockIdx.y + 256 * blockIdx.z;
    const int bg = (linear & 7) + 8 * (linear >> 9);
    const int tt = (linear >> 3) & 63;
    const int b = bg & 3, g = bg >> 2;
    const int t0 = tt * 32;
    const int h = g * 4 + wave;
    const size_t hoff = (size_t)(b * HH + h);
    const __bf16* qhp = Qh + hoff * TS * DD;
    const __bf16* qlp = Ql + hoff * TS * DD;
    const __bf16* khp = Kh + hoff * TS * DD;
    const __bf16* klp = Kl + hoff * TS * DD;
    const __bf16* vhp = VhT + hoff * DD * TS;
    const __bf16* vlp = VlT + hoff * DD * TS;
    _Float16* myp = pp + (size_t)(g - 1) * ((size_t)BB * TS * TS);  // valid only when g>0

    // Q fragments in registers for the whole kernel
    bf16x8 fqh[2][2], fql[2][2];
    #pragma unroll
    for (int tb = 0; tb < 2; ++tb)
        #pragma unroll
        for (int ks = 0; ks < 2; ++ks) {
            size_t o = (size_t)(t0 + tb * 16 + l15) * DD + ks * 32 + quad * 8;
            fqh[tb][ks] = *(const bf16x8*)(qhp + o);
            fql[tb][ks] = *(const bf16x8*)(qlp + o);
        }

    // ---- pass A: l = sum exp(s - MS); no barriers, no LDS ----
    float lacc[2][4];
    #pragma unroll
    for (int tb = 0; tb < 2; ++tb)
        #pragma unroll
        for (int r = 0; r < 4; ++r) lacc[tb][r] = 0.f;

    for (int st = 0; st < 32; ++st) {
        #pragma unroll
        for (int sb = 0; sb < 4; ++sb) {
            size_t ko = (size_t)(st * 64 + sb * 16 + l15) * DD + quad * 8;
            bf16x8 kh0 = *(const bf16x8*)(khp + ko);
            bf16x8 kh1 = *(const bf16x8*)(khp + ko + 32);
            bf16x8 kl0 = *(const bf16x8*)(klp + ko);
            bf16x8 kl1 = *(const bf16x8*)(klp + ko + 32);
            #pragma unroll
            for (int tb = 0; tb < 2; ++tb) {
                f32x4 c = (f32x4){0.f, 0.f, 0.f, 0.f};
                c = mm3(fqh[tb][0], fql[tb][0], kh0, kl0, c);
                c = mm3(fqh[tb][1], fql[tb][1], kh1, kl1, c);
                #pragma unroll
                for (int r = 0; r < 4; ++r)
                    lacc[tb][r] += __expf(c[r] * 0.125f - MS);
            }
        }
    }
    float rf[2][4];
    #pragma unroll
    for (int tb = 0; tb < 2; ++tb)
        #pragma unroll
        for (int r = 0; r < 4; ++r) {
            float v = lacc[tb][r];
            v += __shfl_xor(v, 1);
            v += __shfl_xor(v, 2);
            v += __shfl_xor(v, 4);
            v += __shfl_xor(v, 8);
            rf[tb][r] = 1.0f / v;
        }

    // ---- pass B: exact probs (bitwise-identical score recompute), PV, out1 ----
    f32x4 oacc[2][4];
    #pragma unroll
    for (int tb = 0; tb < 2; ++tb)
        #pragma unroll
        for (int db = 0; db < 4; ++db) oacc[tb][db] = (f32x4){0.f, 0.f, 0.f, 0.f};

    for (int st = 0; st < 32; ++st) {
        #pragma unroll
        for (int sb = 0; sb < 4; ++sb) {
            size_t ko = (size_t)(st * 64 + sb * 16 + l15) * DD + quad * 8;
            bf16x8 kh0 = *(const bf16x8*)(khp + ko);
            bf16x8 kh1 = *(const bf16x8*)(khp + ko + 32);
            bf16x8 kl0 = *(const bf16x8*)(klp + ko);
            bf16x8 kl1 = *(const bf16x8*)(klp + ko + 32);
            #pragma unroll
            for (int tb = 0; tb < 2; ++tb) {
                f32x4 c = (f32x4){0.f, 0.f, 0.f, 0.f};
                c = mm3(fqh[tb][0], fql[tb][0], kh0, kl0, c);
                c = mm3(fqh[tb][1], fql[tb][1], kh1, kl1, c);
                #pragma unroll
                for (int r = 0; r < 4; ++r) {
                    float p = __expf(c[r] * 0.125f - MS) * rf[tb][r];
                    Pt[wave][tb * 16 + quad * 4 + r][sb * 16 + l15] = pk2(p);
                }
            }
        }
        __syncthreads();

        // PV: P A-fragments from own wave's LDS region (v_perm unpack)
        bf16x8 fph[2][2], fpl[2][2];
        #pragma unroll
        for (int tb = 0; tb < 2; ++tb)
            #pragma unroll
            for (int ks = 0; ks < 2; ++ks) {
                const unsigned* ppt = &Pt[wave][tb * 16 + l15][ks * 32 + quad * 8];
                uint4 a = *(const uint4*)ppt;
                uint4 bq = *(const uint4*)(ppt + 4);
                fph[tb][ks] = sel_frag(a, bq, 0x07060302u);
                fpl[tb][ks] = sel_frag(a, bq, 0x05040100u);
            }
        #pragma unroll
        for (int db = 0; db < 4; ++db) {
            size_t vo = (size_t)(db * 16 + l15) * TS + st * 64 + quad * 8;
            bf16x8 vh0 = *(const bf16x8*)(vhp + vo);
            bf16x8 vh1 = *(const bf16x8*)(vhp + vo + 32);
            bf16x8 vl0 = *(const bf16x8*)(vlp + vo);
            bf16x8 vl1 = *(const bf16x8*)(vlp + vo + 32);
            #pragma unroll
            for (int tb = 0; tb < 2; ++tb) {
                f32x4 o = oacc[tb][db];
                o = mm3(fph[tb][0], fpl[tb][0], vh0, vl0, o);
                o = mm3(fph[tb][1], fpl[tb][1], vh1, vl1, o);
                oacc[tb][db] = o;
            }
        }

        // out1 partial: cross-wave (4-head) sum -> one plain vector store per thread
        {
            int row = tid >> 3, s8 = (tid & 7) * 8;
            float vs[8] = {0.f, 0.f, 0.f, 0.f, 0.f, 0.f, 0.f, 0.f};
            #pragma unroll
            for (int w = 0; w < 4; ++w) {
                const unsigned* pw = &Pt[w][row][s8];
                uint4 a = *(const uint4*)pw;
                uint4 bq = *(const uint4*)(pw + 4);
                unsigned uu[8] = {a.x, a.y, a.z, a.w, bq.x, bq.y, bq.z, bq.w};
                #pragma unroll
                for (int j = 0; j < 8; ++j)
                    vs[j] += upk_hi(uu[j]) + upk_lo(uu[j]);
            }
            size_t off = ((size_t)b * TS + t0 + row) * TS + st * 64 + s8;
            if (g == 0) {
                float4 o0, o1v;
                o0.x = vs[0] * 0.0625f; o0.y = vs[1] * 0.0625f;
                o0.z = vs[2] * 0.0625f; o0.w = vs[3] * 0.0625f;
                o1v.x = vs[4] * 0.0625f; o1v.y = vs[5] * 0.0625f;
                o1v.z = vs[6] * 0.0625f; o1v.w = vs[7] * 0.0625f;
                *(float4*)(out1 + off) = o0;
                *(float4*)(out1 + off + 4) = o1v;
            } else {
                f16x8 hv;
                #pragma unroll
                for (int j = 0; j < 8; ++j)
                    hv[j] = (_Float16)(vs[j] * 0.0625f);
                *(f16x8*)(myp + off) = hv;
            }
        }
        __syncthreads();
    }

    // epilogue: avec as hi/lo bf16 [B*T, H*D]
    #pragma unroll
    for (int tb = 0; tb < 2; ++tb)
        #pragma unroll
        for (int db = 0; db < 4; ++db)
            #pragma unroll
            for (int r = 0; r < 4; ++r) {
                int row = t0 + tb * 16 + quad * 4 + r;
                int col = h * 64 + db * 16 + l15;
                float v = oacc[tb][db][r];
                __bf16 hi = (__bf16)v;
                size_t o = ((size_t)b * TS + row) * EE + col;
                avh[o] = hi;
                avl[o] = (__bf16)(v - (float)hi);
            }
}

// ---------------- out1 += p1+p2+p3 (fp16 partials), streaming ----------------
__global__ __launch_bounds__(256) void redk(float* __restrict__ out1,
    const _Float16* __restrict__ pp)
{
    const size_t P = (size_t)BB * TS * TS;
    size_t i = ((size_t)blockIdx.x * 256 + threadIdx.x) * 8;
    float4 a = *(const float4*)(out1 + i);
    float4 c = *(const float4*)(out1 + i + 4);
    f16x8 q1 = *(const f16x8*)(pp + i);
    f16x8 q2 = *(const f16x8*)(pp + P + i);
    f16x8 q3 = *(const f16x8*)(pp + 2 * P + i);
    a.x += (float)q1[0] + (float)q2[0] + (float)q3[0];
    a.y += (float)q1[1] + (float)q2[1] + (float)q3[1];
    a.z += (float)q1[2] + (float)q2[2] + (float)q3[2];
    a.w += (float)q1[3] + (float)q2[3] + (float)q3[3];
    c.x += (float)q1[4] + (float)q2[4] + (float)q3[4];
    c.y += (float)q1[5] + (float)q2[5] + (float)q3[5];
    c.z += (float)q1[6] + (float)q2[6] + (float)q3[6];
    c.w += (float)q1[7] + (float)q2[7] + (float)q3[7];
    *(float4*)(out1 + i) = a;
    *(float4*)(out1 + i + 4) = c;
}

extern "C" void kernel_launch(void* const* d_in, const int* in_sizes, int n_in,
                              void* d_out, int out_size, void* d_ws, size_t ws_size,
                              hipStream_t stream)
{
    const float* query = (const float*)d_in[0];
    const float* key_  = (const float*)d_in[1];
    const float* value = (const float*)d_in[2];
    const float* Wq    = (const float*)d_in[3];
    const float* Wk    = (const float*)d_in[4];
    const float* Wv    = (const float*)d_in[5];
    const float* Wo    = (const float*)d_in[6];

    float* out0 = (float*)d_out;                 // [B,T,E]
    float* out1 = out0 + (size_t)BB * TS * EE;   // [B,T,S]

    char* base = (char*)d_ws;
    const size_t U = 16777216;                   // 16 MB: one bf16 half of an 8.4M-elem tensor
    __bf16* xqh = (__bf16*)(base + 0 * U);
    __bf16* xql = (__bf16*)(base + 1 * U);
    __bf16* xkh = (__bf16*)(base + 2 * U);
    __bf16* xkl = (__bf16*)(base + 3 * U);
    __bf16* xvh = (__bf16*)(base + 4 * U);
    __bf16* xvl = (__bf16*)(base + 5 * U);
    __bf16* Qhp = (__bf16*)(base + 6 * U);
    __bf16* Qlp = (__bf16*)(base + 7 * U);
    __bf16* Khp = (__bf16*)(base + 8 * U);
    __bf16* Klp = (__bf16*)(base + 9 * U);
    __bf16* VhT = (__bf16*)(base + 10 * U);
    __bf16* VlT = (__bf16*)(base + 11 * U);
    __bf16* avh = (__bf16*)(base + 12 * U);
    __bf16* avl = (__bf16*)(base + 13 * U);
    __bf16* wqh = (__bf16*)(base + 14 * U);
    __bf16* wql = wqh + 1048576;
    __bf16* wkh = wql + 1048576;
    __bf16* wkl = wkh + 1048576;
    __bf16* wvh = wkl + 1048576;
    __bf16* wvl = wvh + 1048576;
    __bf16* woh = wvl + 1048576;
    __bf16* wol = woh + 1048576;
    // fp16 out1 partials for g=1..3 alias the xq/xk/xv splits (dead after the
    // three input GEMMs complete): 3 * 32 MB = 96 MB = exactly the 6*U region.
    _Float16* pp = (_Float16*)(base + 0 * U);

    splitk<<<4096, 256, 0, stream>>>(query, xqh, xql);
    splitk<<<4096, 256, 0, stream>>>(key_,  xkh, xkl);
    splitk<<<4096, 256, 0, stream>>>(value, xvh, xvl);
    splitk<<<512,  256, 0, stream>>>(Wq, wqh, wql);
    splitk<<<512,  256, 0, stream>>>(Wk, wkh, wkl);
    splitk<<<512,  256, 0, stream>>>(Wv, wvh, wvl);
    splitk<<<512,  256, 0, stream>>>(Wo, woh, wol);

    dim3 gg(8, 64);
    gemm3<1><<<gg, 256, 0, stream>>>(xqh, xql, wqh, wql, nullptr, Qhp, Qlp, 8192, 1024, 1024);
    gemm3<1><<<gg, 256, 0, stream>>>(xkh, xkl, wkh, wkl, nullptr, Khp, Klp, 8192, 1024, 1024);
    gemm3<2><<<gg, 256, 0, stream>>>(xvh, xvl, wvh, wvl, nullptr, VhT, VlT, 8192, 1024, 1024);

    attn3<<<dim3(64, 4, 4), 256, 0, stream>>>(Qhp, Qlp, Khp, Klp, VhT, VlT, avh, avl, out1, pp);

    redk<<<8192, 256, 0, stream>>>(out1, pp);

    gemm3<0><<<gg, 256, 0, stream>>>(avh, avl, woh, wol, out0, nullptr, nullptr, 8192, 1024, 1024);
}